// Round 13
// baseline (177.939 us; speedup 1.0000x reference)
//
#include <hip/hip_runtime.h>

// Problem: B=32, S=256, M=1024, N=32, O=32.
// out[b][s*32+o] = sum_k exp(-sum_n |proj[b,s,n,o]-proj[b,k,n,o]|),
// proj[b,s,j] = sum_m x[b,s,m] W[j,m],  j = n*32+o.

#define BS 8192      // B*S rows of x
#define MD 1024      // M
#define NO 1024      // N*O

typedef short short8 __attribute__((ext_vector_type(8)));    // 8 bf16 raw bits
typedef float f32x4 __attribute__((ext_vector_type(4)));
typedef _Float16 f16x2 __attribute__((ext_vector_type(2)));
typedef unsigned u32x4 __attribute__((ext_vector_type(4)));

template <typename T, typename F>
__device__ __forceinline__ T bc(F f) { return __builtin_bit_cast(T, f); }

// v_pk_add_f16, both VGPR
__device__ __forceinline__ unsigned pk_add(unsigned a, unsigned b) {
  unsigned d;
  asm("v_pk_add_f16 %0, %1, %2" : "=v"(d) : "v"(a), "v"(b));
  return d;
}

// force a wave-uniform pointer into SGPRs (readfirstlane both halves)
template <typename T>
__device__ __forceinline__ const T* rfl(const T* p) {
  unsigned long long v = (unsigned long long)p;
  unsigned lo = __builtin_amdgcn_readfirstlane((unsigned)v);
  unsigned hi = __builtin_amdgcn_readfirstlane((unsigned)(v >> 32));
  return (const T*)(((unsigned long long)hi << 32) | (unsigned long long)lo);
}

// ---------------- fused cast f32 -> bf16 (RNE) for x and W ----------------
#define N4X ((BS * MD) / 4)   // 2097152 float4 groups in x
#define N4W ((NO * MD) / 4)   //  262144 in W
__global__ __launch_bounds__(256) void cast_bf16_kernel(const float* __restrict__ x,
                                                        const float* __restrict__ W,
                                                        unsigned short* __restrict__ xb,
                                                        unsigned short* __restrict__ wb) {
  int i = blockIdx.x * 256 + threadIdx.x;
  const float* in;
  unsigned short* out;
  if (i < N4X) { in = x; out = xb; }
  else { i -= N4X; if (i >= N4W) return; in = W; out = wb; }
  float4 v = reinterpret_cast<const float4*>(in)[i];
  ushort4 u;
  unsigned b;
  b = __float_as_uint(v.x); u.x = (unsigned short)((b + 0x7FFFu + ((b >> 16) & 1u)) >> 16);
  b = __float_as_uint(v.y); u.y = (unsigned short)((b + 0x7FFFu + ((b >> 16) & 1u)) >> 16);
  b = __float_as_uint(v.z); u.z = (unsigned short)((b + 0x7FFFu + ((b >> 16) & 1u)) >> 16);
  b = __float_as_uint(v.w); u.w = (unsigned short)((b + 0x7FFFu + ((b >> 16) & 1u)) >> 16);
  reinterpret_cast<ushort4*>(out)[i] = u;
}

// ---------------- GEMM (m97-style): C[j,i] = sum_k W[j,k] x[i,k] ----------------
__global__ __launch_bounds__(256) void gemm_kernel(const unsigned short* __restrict__ xb,
                                                   const unsigned short* __restrict__ wb,
                                                   unsigned int* __restrict__ projQ) {
  const int tid = threadIdx.x;
  const int lane = tid & 63;
  const int w = tid >> 6;
  const int wj = w >> 1, wi = w & 1;           // wave quadrant (64x64)
  const int jt = blockIdx.y * 128;
  const int it = blockIdx.x * 128;
  const int c = lane & 15, h = lane >> 4;

  __shared__ unsigned short Wl[128 * 64];      // 16 KB, row-major [row][64k], swizzled
  __shared__ unsigned short Xl[128 * 64];      // 16 KB

  f32x4 acc[4][4] = {};

  for (int k0 = 0; k0 < MD; k0 += 64) {
#pragma unroll
    for (int rep = 0; rep < 4; rep++) {
      const int p = rep * 256 + w * 64 + lane;
      const int row = p >> 3;
      const int ksg = (p & 7) ^ (row & 7);
      const unsigned short* gw = wb + (size_t)(jt + row) * MD + k0 + ksg * 8;
      const unsigned short* gx = xb + (size_t)(it + row) * MD + k0 + ksg * 8;
      __builtin_amdgcn_global_load_lds(
          (const __attribute__((address_space(1))) void*)gw,
          (__attribute__((address_space(3))) void*)((char*)Wl + rep * 4096 + w * 1024),
          16, 0, 0);
      __builtin_amdgcn_global_load_lds(
          (const __attribute__((address_space(1))) void*)gx,
          (__attribute__((address_space(3))) void*)((char*)Xl + rep * 4096 + w * 1024),
          16, 0, 0);
    }
    __syncthreads();

#pragma unroll
    for (int ks = 0; ks < 2; ks++) {
      short8 af[4], bf[4];
#pragma unroll
      for (int mm = 0; mm < 4; mm++) {
        const int rl = wj * 64 + mm * 16 + c;
        af[mm] = *reinterpret_cast<const short8*>(
            (const char*)Wl + rl * 128 + (((ks * 4 + h) ^ (rl & 7)) * 16));
      }
#pragma unroll
      for (int nn = 0; nn < 4; nn++) {
        const int rl = wi * 64 + nn * 16 + c;
        bf[nn] = *reinterpret_cast<const short8*>(
            (const char*)Xl + rl * 128 + (((ks * 4 + h) ^ (rl & 7)) * 16));
      }
#pragma unroll
      for (int mm = 0; mm < 4; mm++)
#pragma unroll
        for (int nn = 0; nn < 4; nn++)
          acc[mm][nn] = __builtin_amdgcn_mfma_f32_16x16x32_bf16(af[mm], bf[nn], acc[mm][nn], 0, 0, 0);
    }
    __syncthreads();
  }

  const int mbase = (jt + wj * 64) >> 6;
#pragma unroll
  for (int mm01 = 0; mm01 < 2; mm01++) {
#pragma unroll
    for (int r = 0; r < 4; r++) {
      const int o = mm01 * 16 + h * 4 + r;
#pragma unroll
      for (int nn = 0; nn < 4; nn++) {
        const size_t i = (size_t)(it + wi * 64 + nn * 16 + c);
        projQ[(((size_t)o << 13) + i) * 16 + mbase] = bc<unsigned int>(
            __builtin_amdgcn_cvt_pkrtz(acc[mm01][nn][r], acc[mm01 + 2][nn][r]));
      }
    }
  }
}

// ---------------- A[o][i] = f32 row-sum via 4 quarter-chains + merge ----------
// Chain shape MUST bit-match dist's quarter-chains (max(x,x)=x) for exact diag.
__global__ __launch_bounds__(256) void asum_kernel(const unsigned int* __restrict__ projQ,
                                                   float* __restrict__ A) {
  int idx = blockIdx.x * 256 + threadIdx.x;   // 32*8192 total
  int gi = idx & 8191, o = idx >> 13;
  const uint4* p = reinterpret_cast<const uint4*>(projQ + (((size_t)o << 13) + gi) * 16);
  uint4 q0 = p[0], q1 = p[1], q2 = p[2], q3 = p[3];
  unsigned aA, aB, aC, aD;
  aA = pk_add(pk_add(pk_add(q0.x, q0.y), q0.z), q0.w);
  aB = pk_add(pk_add(pk_add(q1.x, q1.y), q1.z), q1.w);
  aC = pk_add(pk_add(pk_add(q2.x, q2.y), q2.z), q2.w);
  aD = pk_add(pk_add(pk_add(q3.x, q3.y), q3.z), q3.w);
  unsigned a = pk_add(pk_add(aA, aB), pk_add(aC, aD));
  f16x2 af = bc<f16x2>(a);
  A[((size_t)o << 13) + gi] = (float)af[0] + (float)af[1];
}

// shared chain macros: SGPR-broadcast k-words vs per-lane row words
#define PKMAX(d_, pw_, kw_) asm("v_pk_max_f16 %0, %1, %2" : "=v"(d_) : "v"(pw_), "s"(kw_))
#define PKADDV(d_, a_, b_)  asm("v_pk_add_f16 %0, %1, %2" : "=v"(d_) : "v"(a_), "v"(b_))
#define QCH(q_, pv_, cv_) do { unsigned t_;                 \
    PKMAX(q_, pv_.x, cv_.x);                                 \
    PKMAX(t_, pv_.y, cv_.y); PKADDV(q_, q_, t_);             \
    PKMAX(t_, pv_.z, cv_.z); PKADDV(q_, q_, t_);             \
    PKMAX(t_, pv_.w, cv_.w); PKADDV(q_, q_, t_); } while (0)
#define ROW16(s_, r0_, r1_, r2_, r3_) do {                   \
    unsigned qa_, qb_, qc_, qd_;                             \
    QCH(qa_, r0_, c0); QCH(qb_, r1_, c1);                    \
    QCH(qc_, r2_, c2); QCH(qd_, r3_, c3);                    \
    PKADDV(qa_, qa_, qb_); PKADDV(qc_, qc_, qd_);            \
    PKADDV(s_, qa_, qc_); } while (0)
#define SPREFETCH(v0_, v1_, v2_, v3_, vA_, kr_, ar_) do {               \
    asm("s_load_dwordx4 %0, %1, 0x0"  : "=s"(v0_) : "s"(kr_));          \
    asm("s_load_dwordx4 %0, %1, 0x10" : "=s"(v1_) : "s"(kr_));          \
    asm("s_load_dwordx4 %0, %1, 0x20" : "=s"(v2_) : "s"(kr_));          \
    asm("s_load_dwordx4 %0, %1, 0x30" : "=s"(v3_) : "s"(kr_));          \
    asm("s_load_dword %0, %1, 0x0" : "=s"(vA_) : "s"(ar_)); } while (0)
#define SRETIRE(v0_, v1_, v2_, v3_, vA_)                                \
    asm("s_waitcnt lgkmcnt(0)" : "+s"(v0_), "+s"(v1_), "+s"(v2_), "+s"(v3_), "+s"(vA_))

// ---------------- dist diagonal units: group g vs itself (includes k==i) -------
// grid = 1024(bo) * 4(g), 64 threads. part[slot=g][bo][g*64+t] = sum_{k in g} e.
__global__ __launch_bounds__(64) void dist_diag_kernel(const unsigned int* __restrict__ projQ,
                                                       const float* __restrict__ A,
                                                       float* __restrict__ part) {
  const int t = threadIdx.x;
  const int bid = blockIdx.x;
  const int g = bid & 3, bo = bid >> 2;
  const int o = bo & 31, b = bo >> 5;
  const size_t obase = ((size_t)o << 13) + b * 256;

  const uint4* P = reinterpret_cast<const uint4*>(projQ + (obase + g * 64 + t) * 16);
  const uint4 pa0 = P[0], pa1 = P[1], pa2 = P[2], pa3 = P[3];
  const float Ai = A[obase + g * 64 + t];

  const unsigned* kbase = rfl(projQ + (obase + g * 64) * 16);
  const float* abase = rfl(A + obase + g * 64);

  u32x4 c0, c1, c2, c3; unsigned cA;
  SPREFETCH(c0, c1, c2, c3, cA, kbase, abase);
  SRETIRE(c0, c1, c2, c3, cA);

  float outv = 0.f;
  for (int k = 0; k < 64; ++k) {
    const int kn = (k + 1) & 63;
    const unsigned* kr = kbase + kn * 16;
    u32x4 n0, n1, n2, n3; unsigned nA;
    SPREFETCH(n0, n1, n2, n3, nA, kr, abase + kn);

    unsigned s0;
    ROW16(s0, pa0, pa1, pa2, pa3);
    const float Akf = __builtin_bit_cast(float, cA);
    const f16x2 h0 = bc<f16x2>(s0);
    const float S0 = (float)h0[0] + (float)h0[1];
    outv += exp2f(fmaf(S0, -2.0f, Ai + Akf) * 1.4426950408889634f);

    SRETIRE(n0, n1, n2, n3, nA);
    c0 = n0; c1 = n1; c2 = n2; c3 = n3; cA = nA;
  }

  part[(((size_t)g << 10) + bo) * 256 + g * 64 + t] = outv;
}

// ---------------- dist off-diagonal units: pair (ga<gb), computed ONCE ---------
// grid = 1024(bo) * 6(u), 64 threads. Lane t: row i = ga*64+t; k over gb broadcast.
// outI -> part[gb][bo][ga*64+t];  column sums of eL -> part[ga][bo][gb*64+t].
__global__ __launch_bounds__(64) void dist_off_kernel(const unsigned int* __restrict__ projQ,
                                                      const float* __restrict__ A,
                                                      float* __restrict__ part) {
  const int t = threadIdx.x;
  const int bid = blockIdx.x;
  const int u = bid % 6, bo = bid / 6;
  const int o = bo & 31, b = bo >> 5;
  const size_t obase = ((size_t)o << 13) + b * 256;

  int ga, gb;
  if (u < 3)      { ga = 0; gb = u + 1; }
  else if (u < 5) { ga = 1; gb = u - 1; }
  else            { ga = 2; gb = 3; }

  __shared__ float eL[64][66];   // [k-slot j][lane t], padded: conflict-free rows

  const uint4* P = reinterpret_cast<const uint4*>(projQ + (obase + ga * 64 + t) * 16);
  const uint4 pa0 = P[0], pa1 = P[1], pa2 = P[2], pa3 = P[3];
  const float Ai = A[obase + ga * 64 + t];

  const unsigned* kbase = rfl(projQ + (obase + gb * 64) * 16);
  const float* abase = rfl(A + obase + gb * 64);

  u32x4 c0, c1, c2, c3; unsigned cA;
  SPREFETCH(c0, c1, c2, c3, cA, kbase, abase);
  SRETIRE(c0, c1, c2, c3, cA);

  float outI = 0.f;
  for (int j = 0; j < 64; ++j) {
    const int kn = (j + 1) & 63;
    const unsigned* kr = kbase + kn * 16;
    u32x4 n0, n1, n2, n3; unsigned nA;
    SPREFETCH(n0, n1, n2, n3, nA, kr, abase + kn);

    unsigned s0;
    ROW16(s0, pa0, pa1, pa2, pa3);
    const float Akf = __builtin_bit_cast(float, cA);
    const f16x2 h0 = bc<f16x2>(s0);
    const float S0 = (float)h0[0] + (float)h0[1];
    const float e = exp2f(fmaf(S0, -2.0f, Ai + Akf) * 1.4426950408889634f);
    outI += e;
    eL[j][t] = e;   // symmetric credit: e(i,k) == e(k,i) bitwise

    SRETIRE(n0, n1, n2, n3, nA);
    c0 = n0; c1 = n1; c2 = n2; c3 = n3; cA = nA;
  }

  // i-side store
  part[(((size_t)gb << 10) + bo) * 256 + ga * 64 + t] = outI;

  // k-side: out[gb*64+t] += sum over i (lanes) of e(i, k=gb*64+t)
  // lane t sums row eL[t][0..63] in ascending lane order (bit-matches the
  // i-order the mirror unit would have used).
  __syncthreads();  // single wave: orders LDS writes before reads
  float s = 0.f;
#pragma unroll
  for (int w4 = 0; w4 < 16; ++w4) {
    const float4 v = *reinterpret_cast<const float4*>(&eL[t][w4 * 4]);
    s += v.x; s += v.y; s += v.z; s += v.w;
  }
  part[(((size_t)ga << 10) + bo) * 256 + gb * 64 + t] = s;
}

// ---------------- final: out[b][s*32+o] = sum_slot part[slot][bo][s] ----------
__global__ __launch_bounds__(256) void reduce_kernel(const float* __restrict__ part,
                                                     float* __restrict__ out) {
  const int b = blockIdx.x;
  __shared__ float T[32][257];
  for (int l = threadIdx.x; l < 8192; l += 256) {
    int o = l >> 8, s = l & 255;
    const size_t bo = (size_t)b * 32 + o;
    float v = part[((0 << 10) + bo) * 256 + s] + part[((1 << 10) + bo) * 256 + s]
            + part[((2 << 10) + bo) * 256 + s] + part[((3 << 10) + bo) * 256 + s];
    T[o][s] = v;
  }
  __syncthreads();
  for (int l = threadIdx.x; l < 8192; l += 256)
    out[(size_t)b * 8192 + l] = T[l & 31][l >> 5];
}

extern "C" void kernel_launch(void* const* d_in, const int* in_sizes, int n_in,
                              void* d_out, int out_size, void* d_ws, size_t ws_size,
                              hipStream_t stream) {
  const float* x = (const float*)d_in[0];   // (32,256,1024) f32
  const float* W = (const float*)d_in[1];   // (1024,1024) f32
  float* out = (float*)d_out;               // (32, 8192) f32

  char* ws = (char*)d_ws;
  unsigned short* xb = (unsigned short*)ws;                          // 16 MB
  unsigned short* wbf = (unsigned short*)(ws + (16u << 20));         //  2 MB
  unsigned int* projQ = (unsigned int*)(ws + (18u << 20));           // 16 MB
  float* Abuf = (float*)(ws + (34u << 20));                          //  1 MB
  float* part = (float*)(ws + (35u << 20));                          //  4 MB

  {
    int n4 = N4X + N4W;  // 2359296
    cast_bf16_kernel<<<(n4 + 255) / 256, 256, 0, stream>>>(x, W, xb, wbf);
  }
  {
    dim3 grid(BS / 128, NO / 128);  // (64, 8)
    gemm_kernel<<<grid, 256, 0, stream>>>(xb, wbf, projQ);
  }
  asum_kernel<<<(32 * BS) / 256, 256, 0, stream>>>(projQ, Abuf);
  dist_diag_kernel<<<1024 * 4, 64, 0, stream>>>(projQ, Abuf, part);
  dist_off_kernel<<<1024 * 6, 64, 0, stream>>>(projQ, Abuf, part);
  reduce_kernel<<<32, 256, 0, stream>>>(part, out);
}

// Round 14
// 123.445 us; speedup vs baseline: 1.4415x; 1.4415x over previous
//
#include <hip/hip_runtime.h>

// Problem: B=32, S=256, M=1024, N=32, O=32.
// out[b][s*32+o] = sum_k exp(-sum_n |proj[b,s,n,o]-proj[b,k,n,o]|),
// proj[b,s,j] = sum_m x[b,s,m] W[j,m],  j = n*32+o.

#define BS 8192      // B*S rows of x
#define MD 1024      // M
#define NO 1024      // N*O

typedef short short8 __attribute__((ext_vector_type(8)));    // 8 bf16 raw bits
typedef float f32x4 __attribute__((ext_vector_type(4)));
typedef _Float16 f16x2 __attribute__((ext_vector_type(2)));
typedef unsigned u32x4 __attribute__((ext_vector_type(4)));

template <typename T, typename F>
__device__ __forceinline__ T bc(F f) { return __builtin_bit_cast(T, f); }

// v_pk_add_f16, both VGPR
__device__ __forceinline__ unsigned pk_add(unsigned a, unsigned b) {
  unsigned d;
  asm("v_pk_add_f16 %0, %1, %2" : "=v"(d) : "v"(a), "v"(b));
  return d;
}

// force a wave-uniform pointer into SGPRs (readfirstlane both halves)
template <typename T>
__device__ __forceinline__ const T* rfl(const T* p) {
  unsigned long long v = (unsigned long long)p;
  unsigned lo = __builtin_amdgcn_readfirstlane((unsigned)v);
  unsigned hi = __builtin_amdgcn_readfirstlane((unsigned)(v >> 32));
  return (const T*)(((unsigned long long)hi << 32) | (unsigned long long)lo);
}

// ---------------- fused cast f32 -> bf16 (RNE) for x and W ----------------
#define N4X ((BS * MD) / 4)   // 2097152 float4 groups in x
#define N4W ((NO * MD) / 4)   //  262144 in W
__global__ __launch_bounds__(256) void cast_bf16_kernel(const float* __restrict__ x,
                                                        const float* __restrict__ W,
                                                        unsigned short* __restrict__ xb,
                                                        unsigned short* __restrict__ wb) {
  int i = blockIdx.x * 256 + threadIdx.x;
  const float* in;
  unsigned short* out;
  if (i < N4X) { in = x; out = xb; }
  else { i -= N4X; if (i >= N4W) return; in = W; out = wb; }
  float4 v = reinterpret_cast<const float4*>(in)[i];
  ushort4 u;
  unsigned b;
  b = __float_as_uint(v.x); u.x = (unsigned short)((b + 0x7FFFu + ((b >> 16) & 1u)) >> 16);
  b = __float_as_uint(v.y); u.y = (unsigned short)((b + 0x7FFFu + ((b >> 16) & 1u)) >> 16);
  b = __float_as_uint(v.z); u.z = (unsigned short)((b + 0x7FFFu + ((b >> 16) & 1u)) >> 16);
  b = __float_as_uint(v.w); u.w = (unsigned short)((b + 0x7FFFu + ((b >> 16) & 1u)) >> 16);
  reinterpret_cast<ushort4*>(out)[i] = u;
}

// ---------------- GEMM (m97-style): C[j,i] = sum_k W[j,k] x[i,k] ----------------
__global__ __launch_bounds__(256) void gemm_kernel(const unsigned short* __restrict__ xb,
                                                   const unsigned short* __restrict__ wb,
                                                   unsigned int* __restrict__ projQ) {
  const int tid = threadIdx.x;
  const int lane = tid & 63;
  const int w = tid >> 6;
  const int wj = w >> 1, wi = w & 1;           // wave quadrant (64x64)
  const int jt = blockIdx.y * 128;
  const int it = blockIdx.x * 128;
  const int c = lane & 15, h = lane >> 4;

  __shared__ unsigned short Wl[128 * 64];      // 16 KB, row-major [row][64k], swizzled
  __shared__ unsigned short Xl[128 * 64];      // 16 KB

  f32x4 acc[4][4] = {};

  for (int k0 = 0; k0 < MD; k0 += 64) {
#pragma unroll
    for (int rep = 0; rep < 4; rep++) {
      const int p = rep * 256 + w * 64 + lane;
      const int row = p >> 3;
      const int ksg = (p & 7) ^ (row & 7);
      const unsigned short* gw = wb + (size_t)(jt + row) * MD + k0 + ksg * 8;
      const unsigned short* gx = xb + (size_t)(it + row) * MD + k0 + ksg * 8;
      __builtin_amdgcn_global_load_lds(
          (const __attribute__((address_space(1))) void*)gw,
          (__attribute__((address_space(3))) void*)((char*)Wl + rep * 4096 + w * 1024),
          16, 0, 0);
      __builtin_amdgcn_global_load_lds(
          (const __attribute__((address_space(1))) void*)gx,
          (__attribute__((address_space(3))) void*)((char*)Xl + rep * 4096 + w * 1024),
          16, 0, 0);
    }
    __syncthreads();

#pragma unroll
    for (int ks = 0; ks < 2; ks++) {
      short8 af[4], bf[4];
#pragma unroll
      for (int mm = 0; mm < 4; mm++) {
        const int rl = wj * 64 + mm * 16 + c;
        af[mm] = *reinterpret_cast<const short8*>(
            (const char*)Wl + rl * 128 + (((ks * 4 + h) ^ (rl & 7)) * 16));
      }
#pragma unroll
      for (int nn = 0; nn < 4; nn++) {
        const int rl = wi * 64 + nn * 16 + c;
        bf[nn] = *reinterpret_cast<const short8*>(
            (const char*)Xl + rl * 128 + (((ks * 4 + h) ^ (rl & 7)) * 16));
      }
#pragma unroll
      for (int mm = 0; mm < 4; mm++)
#pragma unroll
        for (int nn = 0; nn < 4; nn++)
          acc[mm][nn] = __builtin_amdgcn_mfma_f32_16x16x32_bf16(af[mm], bf[nn], acc[mm][nn], 0, 0, 0);
    }
    __syncthreads();
  }

  const int mbase = (jt + wj * 64) >> 6;
#pragma unroll
  for (int mm01 = 0; mm01 < 2; mm01++) {
#pragma unroll
    for (int r = 0; r < 4; r++) {
      const int o = mm01 * 16 + h * 4 + r;
#pragma unroll
      for (int nn = 0; nn < 4; nn++) {
        const size_t i = (size_t)(it + wi * 64 + nn * 16 + c);
        projQ[(((size_t)o << 13) + i) * 16 + mbase] = bc<unsigned int>(
            __builtin_amdgcn_cvt_pkrtz(acc[mm01][nn][r], acc[mm01 + 2][nn][r]));
      }
    }
  }
}

// ---------------- A[o][i] = f32 row-sum via 4 quarter-chains + merge ----------
// Chain shape MUST bit-match dist's quarter-chains (max(x,x)=x) for exact diag.
__global__ __launch_bounds__(256) void asum_kernel(const unsigned int* __restrict__ projQ,
                                                   float* __restrict__ A) {
  int idx = blockIdx.x * 256 + threadIdx.x;   // 32*8192 total
  int gi = idx & 8191, o = idx >> 13;
  const uint4* p = reinterpret_cast<const uint4*>(projQ + (((size_t)o << 13) + gi) * 16);
  uint4 q0 = p[0], q1 = p[1], q2 = p[2], q3 = p[3];
  unsigned aA, aB, aC, aD;
  aA = pk_add(pk_add(pk_add(q0.x, q0.y), q0.z), q0.w);
  aB = pk_add(pk_add(pk_add(q1.x, q1.y), q1.z), q1.w);
  aC = pk_add(pk_add(pk_add(q2.x, q2.y), q2.z), q2.w);
  aD = pk_add(pk_add(pk_add(q3.x, q3.y), q3.z), q3.w);
  unsigned a = pk_add(pk_add(aA, aB), pk_add(aC, aD));
  f16x2 af = bc<f16x2>(a);
  A[((size_t)o << 13) + gi] = (float)af[0] + (float)af[1];
}

// shared chain macros: SGPR-broadcast k-words vs per-lane row words
#define PKMAX(d_, pw_, kw_) asm("v_pk_max_f16 %0, %1, %2" : "=v"(d_) : "v"(pw_), "s"(kw_))
#define PKADDV(d_, a_, b_)  asm("v_pk_add_f16 %0, %1, %2" : "=v"(d_) : "v"(a_), "v"(b_))
#define QCH(q_, pv_, cv_) do { unsigned t_;                 \
    PKMAX(q_, pv_.x, cv_.x);                                 \
    PKMAX(t_, pv_.y, cv_.y); PKADDV(q_, q_, t_);             \
    PKMAX(t_, pv_.z, cv_.z); PKADDV(q_, q_, t_);             \
    PKMAX(t_, pv_.w, cv_.w); PKADDV(q_, q_, t_); } while (0)
#define ROW16(s_, r0_, r1_, r2_, r3_) do {                   \
    unsigned qa_, qb_, qc_, qd_;                             \
    QCH(qa_, r0_, c0); QCH(qb_, r1_, c1);                    \
    QCH(qc_, r2_, c2); QCH(qd_, r3_, c3);                    \
    PKADDV(qa_, qa_, qb_); PKADDV(qc_, qc_, qd_);            \
    PKADDV(s_, qa_, qc_); } while (0)
#define SPREFETCH(v0_, v1_, v2_, v3_, vA_, kr_, ar_) do {               \
    asm("s_load_dwordx4 %0, %1, 0x0"  : "=s"(v0_) : "s"(kr_));          \
    asm("s_load_dwordx4 %0, %1, 0x10" : "=s"(v1_) : "s"(kr_));          \
    asm("s_load_dwordx4 %0, %1, 0x20" : "=s"(v2_) : "s"(kr_));          \
    asm("s_load_dwordx4 %0, %1, 0x30" : "=s"(v3_) : "s"(kr_));          \
    asm("s_load_dword %0, %1, 0x0" : "=s"(vA_) : "s"(ar_)); } while (0)
#define SRETIRE(v0_, v1_, v2_, v3_, vA_)                                \
    asm("s_waitcnt lgkmcnt(0)" : "+s"(v0_), "+s"(v1_), "+s"(v2_), "+s"(v3_), "+s"(vA_))

#define L2E 1.4426950408889634f

// ---------------- phase 2: symmetric distances, one block per (b,o) -----------
// Wave w: k-group w vs i-groups {w, w+1 [, w+2]} (waves 0,1: 3 rows; 2,3: 2).
// Covers 4 diag + 6 off units (each off pair once). Off e-values staged to
// eL (f16) for the mirror (column-sum) credit. 16 (slot,row) outputs, each
// written once -> deterministic; block writes out directly.
__global__ __launch_bounds__(256) void dist_kernel(const unsigned int* __restrict__ projQ,
                                                   const float* __restrict__ A,
                                                   float* __restrict__ out) {
  const int tid = threadIdx.x;
  const int t = tid & 63;   // lane
  const int w = tid >> 6;   // wave
  const int o = blockIdx.x & 31, b = blockIdx.x >> 5;
  const size_t obase = ((size_t)o << 13) + b * 256;

  __shared__ unsigned short eLs[6 * 64 * 66];  // 50688 B; reused as outp later

  const int gA = w;                 // diag group
  const int gB = (w + 1) & 3;       // off row 1
  const int gC = (w + 2) & 3;       // off row 2 (waves 0,1 only)
  const int uB = (w < 2) ? 2 * w : w + 2;   // eL unit ids: {0,2,4,5}
  // uC = 2*w+1 for w<2: {1,3}

  const uint4* PA = reinterpret_cast<const uint4*>(projQ + (obase + gA * 64 + t) * 16);
  const uint4 pa0 = PA[0], pa1 = PA[1], pa2 = PA[2], pa3 = PA[3];
  const uint4* PB = reinterpret_cast<const uint4*>(projQ + (obase + gB * 64 + t) * 16);
  const uint4 pb0 = PB[0], pb1 = PB[1], pb2 = PB[2], pb3 = PB[3];
  uint4 pc0 = {0, 0, 0, 0}, pc1 = {0, 0, 0, 0}, pc2 = {0, 0, 0, 0}, pc3 = {0, 0, 0, 0};
  float AiC = 0.f;
  if (w < 2) {
    const uint4* PC = reinterpret_cast<const uint4*>(projQ + (obase + gC * 64 + t) * 16);
    pc0 = PC[0]; pc1 = PC[1]; pc2 = PC[2]; pc3 = PC[3];
    AiC = A[obase + gC * 64 + t];
  }
  const float AiA = A[obase + gA * 64 + t];
  const float AiB = A[obase + gB * 64 + t];

  const unsigned* kbase = rfl(projQ + (obase + w * 64) * 16);
  const float* abase = rfl(A + obase + w * 64);

  u32x4 c0, c1, c2, c3; unsigned cA;
  SPREFETCH(c0, c1, c2, c3, cA, kbase, abase);
  SRETIRE(c0, c1, c2, c3, cA);

  unsigned short* eBp = eLs + uB * 4224 + t * 66;

  float accA = 0.f, accB = 0.f, accC = 0.f;
  if (w < 2) {
    unsigned short* eCp = eLs + (2 * w + 1) * 4224 + t * 66;
    for (int j = 0; j < 64; ++j) {
      const int kn = (j + 1) & 63;
      const unsigned* kr = kbase + kn * 16;
      u32x4 n0, n1, n2, n3; unsigned nA;
      SPREFETCH(n0, n1, n2, n3, nA, kr, abase + kn);

      unsigned s0, s1, s2;
      ROW16(s0, pa0, pa1, pa2, pa3);
      ROW16(s1, pb0, pb1, pb2, pb3);
      ROW16(s2, pc0, pc1, pc2, pc3);
      const float Akf = __builtin_bit_cast(float, cA);
      const f16x2 h0 = bc<f16x2>(s0), h1 = bc<f16x2>(s1), h2 = bc<f16x2>(s2);
      const float SA = (float)h0[0] + (float)h0[1];
      const float SB = (float)h1[0] + (float)h1[1];
      const float SC = (float)h2[0] + (float)h2[1];
      const float eA = exp2f(fmaf(SA, -2.0f, AiA + Akf) * L2E);
      const float eB = exp2f(fmaf(SB, -2.0f, AiB + Akf) * L2E);
      const float eC = exp2f(fmaf(SC, -2.0f, AiC + Akf) * L2E);
      accA += eA; accB += eB; accC += eC;
      eBp[j] = bc<unsigned short>((_Float16)eB);
      eCp[j] = bc<unsigned short>((_Float16)eC);

      SRETIRE(n0, n1, n2, n3, nA);
      c0 = n0; c1 = n1; c2 = n2; c3 = n3; cA = nA;
    }
  } else {
    for (int j = 0; j < 64; ++j) {
      const int kn = (j + 1) & 63;
      const unsigned* kr = kbase + kn * 16;
      u32x4 n0, n1, n2, n3; unsigned nA;
      SPREFETCH(n0, n1, n2, n3, nA, kr, abase + kn);

      unsigned s0, s1;
      ROW16(s0, pa0, pa1, pa2, pa3);
      ROW16(s1, pb0, pb1, pb2, pb3);
      const float Akf = __builtin_bit_cast(float, cA);
      const f16x2 h0 = bc<f16x2>(s0), h1 = bc<f16x2>(s1);
      const float SA = (float)h0[0] + (float)h0[1];
      const float SB = (float)h1[0] + (float)h1[1];
      const float eA = exp2f(fmaf(SA, -2.0f, AiA + Akf) * L2E);
      const float eB = exp2f(fmaf(SB, -2.0f, AiB + Akf) * L2E);
      accA += eA; accB += eB;
      eBp[j] = bc<unsigned short>((_Float16)eB);

      SRETIRE(n0, n1, n2, n3, nA);
      c0 = n0; c1 = n1; c2 = n2; c3 = n3; cA = nA;
    }
  }
  __syncthreads();

  // column sums (mirror credits). units: w0: u2 ; w1: u3 ; w2: u0,u4 ; w3: u1,u5
  float cs0 = 0.f, cs1 = 0.f;
  {
    const int v0 = (w == 0) ? 2 : (w == 1) ? 3 : (w == 2) ? 0 : 1;
    const unsigned* rp = reinterpret_cast<const unsigned*>(eLs + v0 * 4224 + t * 66);
#pragma unroll
    for (int kk = 0; kk < 32; ++kk) {
      const f16x2 hv = bc<f16x2>(rp[kk]);
      cs0 += (float)hv[0]; cs0 += (float)hv[1];
    }
    if (w >= 2) {
      const unsigned* rp1 = reinterpret_cast<const unsigned*>(eLs + (w + 2) * 4224 + t * 66);
#pragma unroll
      for (int kk = 0; kk < 32; ++kk) {
        const f16x2 hv = bc<f16x2>(rp1[kk]);
        cs1 += (float)hv[0]; cs1 += (float)hv[1];
      }
    }
  }
  __syncthreads();

  // write the 16 contribution slots (each exactly once), reusing smem
  float* outp = (float*)eLs;   // [4 slots][256 rows]
  outp[0 * 256 + gA * 64 + t] = accA;                      // diag
  const int slotB = (w == 0) ? 1 : (w == 3) ? 3 : 2;
  outp[slotB * 256 + gB * 64 + t] = accB;                  // off i-side B
  if (w < 2) outp[1 * 256 + gC * 64 + t] = accC;           // off i-side C
  if (w == 0)      outp[2 * 256 + 64 + t] = cs0;           // u2 -> g1
  else if (w == 1) outp[3 * 256 + 64 + t] = cs0;           // u3 -> g1
  else if (w == 2) { outp[1 * 256 + t] = cs0;              // u0 -> g0
                     outp[3 * 256 + 128 + t] = cs1; }      // u4 -> g2
  else             { outp[2 * 256 + t] = cs0;              // u1 -> g0
                     outp[3 * 256 + 192 + t] = cs1; }      // u5 -> g3
  __syncthreads();

  const float v = ((outp[tid] + outp[256 + tid]) + outp[512 + tid]) + outp[768 + tid];
  out[(size_t)b * 8192 + (size_t)tid * 32 + o] = v;
}

extern "C" void kernel_launch(void* const* d_in, const int* in_sizes, int n_in,
                              void* d_out, int out_size, void* d_ws, size_t ws_size,
                              hipStream_t stream) {
  const float* x = (const float*)d_in[0];   // (32,256,1024) f32
  const float* W = (const float*)d_in[1];   // (1024,1024) f32
  float* out = (float*)d_out;               // (32, 8192) f32

  char* ws = (char*)d_ws;
  unsigned short* xb = (unsigned short*)ws;                          // 16 MB
  unsigned short* wbf = (unsigned short*)(ws + (16u << 20));         //  2 MB
  unsigned int* projQ = (unsigned int*)(ws + (18u << 20));           // 16 MB
  float* Abuf = (float*)(ws + (34u << 20));                          //  1 MB

  {
    int n4 = N4X + N4W;  // 2359296
    cast_bf16_kernel<<<(n4 + 255) / 256, 256, 0, stream>>>(x, W, xb, wbf);
  }
  {
    dim3 grid(BS / 128, NO / 128);  // (64, 8)
    gemm_kernel<<<grid, 256, 0, stream>>>(xb, wbf, projQ);
  }
  asum_kernel<<<(32 * BS) / 256, 256, 0, stream>>>(projQ, Abuf);
  dist_kernel<<<32 * 32, 256, 0, stream>>>(projQ, Abuf, out);
}

// Round 15
// 121.486 us; speedup vs baseline: 1.4647x; 1.0161x over previous
//
#include <hip/hip_runtime.h>

// Problem: B=32, S=256, M=1024, N=32, O=32.
// out[b][s*32+o] = sum_k exp(-sum_n |proj[b,s,n,o]-proj[b,k,n,o]|),
// proj[b,s,j] = sum_m x[b,s,m] W[j,m],  j = n*32+o.

#define BS 8192      // B*S rows of x
#define MD 1024      // M
#define NO 1024      // N*O

typedef short short8 __attribute__((ext_vector_type(8)));    // 8 bf16 raw bits
typedef float f32x4 __attribute__((ext_vector_type(4)));
typedef _Float16 f16x2 __attribute__((ext_vector_type(2)));
typedef unsigned u32x4 __attribute__((ext_vector_type(4)));

template <typename T, typename F>
__device__ __forceinline__ T bc(F f) { return __builtin_bit_cast(T, f); }

// v_pk_add_f16, both VGPR
__device__ __forceinline__ unsigned pk_add(unsigned a, unsigned b) {
  unsigned d;
  asm("v_pk_add_f16 %0, %1, %2" : "=v"(d) : "v"(a), "v"(b));
  return d;
}

// force a wave-uniform pointer into SGPRs (readfirstlane both halves)
template <typename T>
__device__ __forceinline__ const T* rfl(const T* p) {
  unsigned long long v = (unsigned long long)p;
  unsigned lo = __builtin_amdgcn_readfirstlane((unsigned)v);
  unsigned hi = __builtin_amdgcn_readfirstlane((unsigned)(v >> 32));
  return (const T*)(((unsigned long long)hi << 32) | (unsigned long long)lo);
}

// ---------------- fused cast f32 -> bf16 (RNE) for x and W ----------------
#define N4X ((BS * MD) / 4)   // 2097152 float4 groups in x
#define N4W ((NO * MD) / 4)   //  262144 in W
__global__ __launch_bounds__(256) void cast_bf16_kernel(const float* __restrict__ x,
                                                        const float* __restrict__ W,
                                                        unsigned short* __restrict__ xb,
                                                        unsigned short* __restrict__ wb) {
  int i = blockIdx.x * 256 + threadIdx.x;
  const float* in;
  unsigned short* out;
  if (i < N4X) { in = x; out = xb; }
  else { i -= N4X; if (i >= N4W) return; in = W; out = wb; }
  float4 v = reinterpret_cast<const float4*>(in)[i];
  ushort4 u;
  unsigned b;
  b = __float_as_uint(v.x); u.x = (unsigned short)((b + 0x7FFFu + ((b >> 16) & 1u)) >> 16);
  b = __float_as_uint(v.y); u.y = (unsigned short)((b + 0x7FFFu + ((b >> 16) & 1u)) >> 16);
  b = __float_as_uint(v.z); u.z = (unsigned short)((b + 0x7FFFu + ((b >> 16) & 1u)) >> 16);
  b = __float_as_uint(v.w); u.w = (unsigned short)((b + 0x7FFFu + ((b >> 16) & 1u)) >> 16);
  reinterpret_cast<ushort4*>(out)[i] = u;
}

// ---------------- GEMM (m97-style): C[j,i] = sum_k W[j,k] x[i,k] ----------------
__global__ __launch_bounds__(256) void gemm_kernel(const unsigned short* __restrict__ xb,
                                                   const unsigned short* __restrict__ wb,
                                                   unsigned int* __restrict__ projQ) {
  const int tid = threadIdx.x;
  const int lane = tid & 63;
  const int w = tid >> 6;
  const int wj = w >> 1, wi = w & 1;           // wave quadrant (64x64)
  const int jt = blockIdx.y * 128;
  const int it = blockIdx.x * 128;
  const int c = lane & 15, h = lane >> 4;

  __shared__ unsigned short Wl[128 * 64];      // 16 KB, row-major [row][64k], swizzled
  __shared__ unsigned short Xl[128 * 64];      // 16 KB

  f32x4 acc[4][4] = {};

  for (int k0 = 0; k0 < MD; k0 += 64) {
#pragma unroll
    for (int rep = 0; rep < 4; rep++) {
      const int p = rep * 256 + w * 64 + lane;
      const int row = p >> 3;
      const int ksg = (p & 7) ^ (row & 7);
      const unsigned short* gw = wb + (size_t)(jt + row) * MD + k0 + ksg * 8;
      const unsigned short* gx = xb + (size_t)(it + row) * MD + k0 + ksg * 8;
      __builtin_amdgcn_global_load_lds(
          (const __attribute__((address_space(1))) void*)gw,
          (__attribute__((address_space(3))) void*)((char*)Wl + rep * 4096 + w * 1024),
          16, 0, 0);
      __builtin_amdgcn_global_load_lds(
          (const __attribute__((address_space(1))) void*)gx,
          (__attribute__((address_space(3))) void*)((char*)Xl + rep * 4096 + w * 1024),
          16, 0, 0);
    }
    __syncthreads();

#pragma unroll
    for (int ks = 0; ks < 2; ks++) {
      short8 af[4], bf[4];
#pragma unroll
      for (int mm = 0; mm < 4; mm++) {
        const int rl = wj * 64 + mm * 16 + c;
        af[mm] = *reinterpret_cast<const short8*>(
            (const char*)Wl + rl * 128 + (((ks * 4 + h) ^ (rl & 7)) * 16));
      }
#pragma unroll
      for (int nn = 0; nn < 4; nn++) {
        const int rl = wi * 64 + nn * 16 + c;
        bf[nn] = *reinterpret_cast<const short8*>(
            (const char*)Xl + rl * 128 + (((ks * 4 + h) ^ (rl & 7)) * 16));
      }
#pragma unroll
      for (int mm = 0; mm < 4; mm++)
#pragma unroll
        for (int nn = 0; nn < 4; nn++)
          acc[mm][nn] = __builtin_amdgcn_mfma_f32_16x16x32_bf16(af[mm], bf[nn], acc[mm][nn], 0, 0, 0);
    }
    __syncthreads();
  }

  const int mbase = (jt + wj * 64) >> 6;
#pragma unroll
  for (int mm01 = 0; mm01 < 2; mm01++) {
#pragma unroll
    for (int r = 0; r < 4; r++) {
      const int o = mm01 * 16 + h * 4 + r;
#pragma unroll
      for (int nn = 0; nn < 4; nn++) {
        const size_t i = (size_t)(it + wi * 64 + nn * 16 + c);
        projQ[(((size_t)o << 13) + i) * 16 + mbase] = bc<unsigned int>(
            __builtin_amdgcn_cvt_pkrtz(acc[mm01][nn][r], acc[mm01 + 2][nn][r]));
      }
    }
  }
}

// shared chain macros: SGPR-broadcast k-words vs per-lane row words
#define PKMAX(d_, pw_, kw_) asm("v_pk_max_f16 %0, %1, %2" : "=v"(d_) : "v"(pw_), "s"(kw_))
#define PKADDV(d_, a_, b_)  asm("v_pk_add_f16 %0, %1, %2" : "=v"(d_) : "v"(a_), "v"(b_))
#define QCH(q_, pv_, cv_) do { unsigned t_;                 \
    PKMAX(q_, pv_.x, cv_.x);                                 \
    PKMAX(t_, pv_.y, cv_.y); PKADDV(q_, q_, t_);             \
    PKMAX(t_, pv_.z, cv_.z); PKADDV(q_, q_, t_);             \
    PKMAX(t_, pv_.w, cv_.w); PKADDV(q_, q_, t_); } while (0)
#define ROW16(s_, r0_, r1_, r2_, r3_) do {                   \
    unsigned qa_, qb_, qc_, qd_;                             \
    QCH(qa_, r0_, c0); QCH(qb_, r1_, c1);                    \
    QCH(qc_, r2_, c2); QCH(qd_, r3_, c3);                    \
    PKADDV(qa_, qa_, qb_); PKADDV(qc_, qc_, qd_);            \
    PKADDV(s_, qa_, qc_); } while (0)
#define SPREFETCH(v0_, v1_, v2_, v3_, kr_) do {                         \
    asm("s_load_dwordx4 %0, %1, 0x0"  : "=s"(v0_) : "s"(kr_));          \
    asm("s_load_dwordx4 %0, %1, 0x10" : "=s"(v1_) : "s"(kr_));          \
    asm("s_load_dwordx4 %0, %1, 0x20" : "=s"(v2_) : "s"(kr_));          \
    asm("s_load_dwordx4 %0, %1, 0x30" : "=s"(v3_) : "s"(kr_)); } while (0)
#define SRETIRE(v0_, v1_, v2_, v3_)                                     \
    asm("s_waitcnt lgkmcnt(0)" : "+s"(v0_), "+s"(v1_), "+s"(v2_), "+s"(v3_))

#define L2E 1.4426950408889634f
#define EU 2176   // shorts per eL unit: 64 rows x 34 (32 data + 2 pad)

// ---------------- phase 2: symmetric distances + folded A, one block per (b,o) ---
// Wave w: k-group w vs i-groups {w, w+1 [, w+2]} (waves 0,1: 3 rows; 2,3: 2).
// A computed in-block (bit-matched chain). k-loop split in two 32-iter halves,
// col-sums after each half reuse a half-size eL -> LDS ~27.9 KB.
__global__ __launch_bounds__(256) void dist_kernel(const unsigned int* __restrict__ projQ,
                                                   float* __restrict__ out) {
  const int tid = threadIdx.x;
  const int t = tid & 63;   // lane
  const int w = tid >> 6;   // wave
  const int o = blockIdx.x & 31, b = blockIdx.x >> 5;
  const size_t obase = ((size_t)o << 13) + b * 256;

  __shared__ unsigned short eLs[6 * EU];  // 26112 B; reused as outp later
  __shared__ float A_lds[256];            // 1 KB

  const int gA = w;                 // diag group
  const int gB = (w + 1) & 3;       // off row 1
  const int gC = (w + 2) & 3;       // off row 2 (waves 0,1 only)
  const int uB = (w < 2) ? 2 * w : w + 2;   // eL unit ids: {0,2,4,5}; uC = 2w+1

  const uint4* PA = reinterpret_cast<const uint4*>(projQ + (obase + gA * 64 + t) * 16);
  const uint4 pa0 = PA[0], pa1 = PA[1], pa2 = PA[2], pa3 = PA[3];
  const uint4* PB = reinterpret_cast<const uint4*>(projQ + (obase + gB * 64 + t) * 16);
  const uint4 pb0 = PB[0], pb1 = PB[1], pb2 = PB[2], pb3 = PB[3];
  uint4 pc0 = {0, 0, 0, 0}, pc1 = {0, 0, 0, 0}, pc2 = {0, 0, 0, 0}, pc3 = {0, 0, 0, 0};
  if (w < 2) {
    const uint4* PC = reinterpret_cast<const uint4*>(projQ + (obase + gC * 64 + t) * 16);
    pc0 = PC[0]; pc1 = PC[1]; pc2 = PC[2]; pc3 = PC[3];
  }

  // folded asum: A[g_w[t]] from pa regs; chain shape bit-matches ROW16 with
  // max(x,x)=x: QCH = ((m0+m1)+m2)+m3, merge = (qa+qb)+(qc+qd).
  {
    unsigned aA = pk_add(pk_add(pk_add(pa0.x, pa0.y), pa0.z), pa0.w);
    unsigned aB = pk_add(pk_add(pk_add(pa1.x, pa1.y), pa1.z), pa1.w);
    unsigned aC = pk_add(pk_add(pk_add(pa2.x, pa2.y), pa2.z), pa2.w);
    unsigned aD = pk_add(pk_add(pk_add(pa3.x, pa3.y), pa3.z), pa3.w);
    unsigned a = pk_add(pk_add(aA, aB), pk_add(aC, aD));
    f16x2 af = bc<f16x2>(a);
    A_lds[w * 64 + t] = (float)af[0] + (float)af[1];
  }
  __syncthreads();

  const float AiA = A_lds[gA * 64 + t];
  const float AiB = A_lds[gB * 64 + t];
  const float AiC = (w < 2) ? A_lds[gC * 64 + t] : 0.f;

  const unsigned* kbase = rfl(projQ + (obase + w * 64) * 16);

  u32x4 c0, c1, c2, c3;
  SPREFETCH(c0, c1, c2, c3, kbase);
  float cAk = A_lds[w * 64];
  SRETIRE(c0, c1, c2, c3);

  unsigned short* eBp = eLs + uB * EU + t * 34;
  unsigned short* eCp = eLs + (2 * w + 1) * EU + t * 34;  // valid only w<2
  const int v0 = (w == 0) ? 2 : (w == 1) ? 3 : (w == 2) ? 0 : 1;
  const unsigned* rp0 = reinterpret_cast<const unsigned*>(eLs + v0 * EU + t * 34);
  const unsigned* rp1 = reinterpret_cast<const unsigned*>(eLs + (w + 2) * EU + t * 34);

  float accA = 0.f, accB = 0.f, accC = 0.f;
  float cs0 = 0.f, cs1 = 0.f;

  for (int half = 0; half < 2; ++half) {
    if (w < 2) {
      for (int j = 0; j < 32; ++j) {
        const int kn = (half * 32 + j + 1) & 63;
        const unsigned* kr = kbase + kn * 16;
        u32x4 n0, n1, n2, n3;
        SPREFETCH(n0, n1, n2, n3, kr);
        const float nAk = A_lds[w * 64 + kn];

        unsigned s0, s1, s2;
        ROW16(s0, pa0, pa1, pa2, pa3);
        ROW16(s1, pb0, pb1, pb2, pb3);
        ROW16(s2, pc0, pc1, pc2, pc3);
        const f16x2 h0 = bc<f16x2>(s0), h1 = bc<f16x2>(s1), h2 = bc<f16x2>(s2);
        const float SA = (float)h0[0] + (float)h0[1];
        const float SB = (float)h1[0] + (float)h1[1];
        const float SC = (float)h2[0] + (float)h2[1];
        const float eA = exp2f(fmaf(SA, -2.0f, AiA + cAk) * L2E);
        const float eB = exp2f(fmaf(SB, -2.0f, AiB + cAk) * L2E);
        const float eC = exp2f(fmaf(SC, -2.0f, AiC + cAk) * L2E);
        accA += eA; accB += eB; accC += eC;
        eBp[j] = bc<unsigned short>((_Float16)eB);
        eCp[j] = bc<unsigned short>((_Float16)eC);

        SRETIRE(n0, n1, n2, n3);
        c0 = n0; c1 = n1; c2 = n2; c3 = n3; cAk = nAk;
      }
    } else {
      for (int j = 0; j < 32; ++j) {
        const int kn = (half * 32 + j + 1) & 63;
        const unsigned* kr = kbase + kn * 16;
        u32x4 n0, n1, n2, n3;
        SPREFETCH(n0, n1, n2, n3, kr);
        const float nAk = A_lds[w * 64 + kn];

        unsigned s0, s1;
        ROW16(s0, pa0, pa1, pa2, pa3);
        ROW16(s1, pb0, pb1, pb2, pb3);
        const f16x2 h0 = bc<f16x2>(s0), h1 = bc<f16x2>(s1);
        const float SA = (float)h0[0] + (float)h0[1];
        const float SB = (float)h1[0] + (float)h1[1];
        const float eA = exp2f(fmaf(SA, -2.0f, AiA + cAk) * L2E);
        const float eB = exp2f(fmaf(SB, -2.0f, AiB + cAk) * L2E);
        accA += eA; accB += eB;
        eBp[j] = bc<unsigned short>((_Float16)eB);

        SRETIRE(n0, n1, n2, n3);
        c0 = n0; c1 = n1; c2 = n2; c3 = n3; cAk = nAk;
      }
    }
    __syncthreads();   // eL half complete

    // col-sum partials (mirror credits): w0:u2, w1:u3, w2:{u0,u4}, w3:{u1,u5}
#pragma unroll
    for (int kk = 0; kk < 16; ++kk) {
      const f16x2 hv = bc<f16x2>(rp0[kk]);
      cs0 += (float)hv[0]; cs0 += (float)hv[1];
    }
    if (w >= 2) {
#pragma unroll
      for (int kk = 0; kk < 16; ++kk) {
        const f16x2 hv = bc<f16x2>(rp1[kk]);
        cs1 += (float)hv[0]; cs1 += (float)hv[1];
      }
    }
    __syncthreads();   // col-sums done before eL reuse (next half / outp)
  }

  // write the 16 contribution slots (each exactly once), reusing smem
  float* outp = (float*)eLs;   // [4 slots][256 rows]
  outp[0 * 256 + gA * 64 + t] = accA;                      // diag
  const int slotB = (w == 0) ? 1 : (w == 3) ? 3 : 2;
  outp[slotB * 256 + gB * 64 + t] = accB;                  // off i-side B
  if (w < 2) outp[1 * 256 + gC * 64 + t] = accC;           // off i-side C
  if (w == 0)      outp[2 * 256 + 64 + t] = cs0;           // u2 -> g1
  else if (w == 1) outp[3 * 256 + 64 + t] = cs0;           // u3 -> g1
  else if (w == 2) { outp[1 * 256 + t] = cs0;              // u0 -> g0
                     outp[3 * 256 + 128 + t] = cs1; }      // u4 -> g2
  else             { outp[2 * 256 + t] = cs0;              // u1 -> g0
                     outp[3 * 256 + 192 + t] = cs1; }      // u5 -> g3
  __syncthreads();

  const float v = ((outp[tid] + outp[256 + tid]) + outp[512 + tid]) + outp[768 + tid];
  out[(size_t)b * 8192 + (size_t)tid * 32 + o] = v;
}

extern "C" void kernel_launch(void* const* d_in, const int* in_sizes, int n_in,
                              void* d_out, int out_size, void* d_ws, size_t ws_size,
                              hipStream_t stream) {
  const float* x = (const float*)d_in[0];   // (32,256,1024) f32
  const float* W = (const float*)d_in[1];   // (1024,1024) f32
  float* out = (float*)d_out;               // (32, 8192) f32

  char* ws = (char*)d_ws;
  unsigned short* xb = (unsigned short*)ws;                          // 16 MB
  unsigned short* wbf = (unsigned short*)(ws + (16u << 20));         //  2 MB
  unsigned int* projQ = (unsigned int*)(ws + (18u << 20));           // 16 MB

  {
    int n4 = N4X + N4W;  // 2359296
    cast_bf16_kernel<<<(n4 + 255) / 256, 256, 0, stream>>>(x, W, xb, wbf);
  }
  {
    dim3 grid(BS / 128, NO / 128);  // (64, 8)
    gemm_kernel<<<grid, 256, 0, stream>>>(xb, wbf, projQ);
  }
  dist_kernel<<<32 * 32, 256, 0, stream>>>(projQ, out);
}